// Round 4
// baseline (255.529 us; speedup 1.0000x reference)
//
#include <hip/hip_runtime.h>
#include <hip/hip_bf16.h>

// Problem constants: E=1024, H=16, HD=64, T=1024, B=4, S=1024.
// d_in: 0 query(T,B,E) f32, 1 key(S,B,E), 2 value(S,B,E), 3 in_proj_weight(3E,E),
//       4 in_proj_bias(3E), 5 out_w(E,E), 6 out_b(E).
// d_out: attn(T,B,E) f32 [4M] then avg_w(B,T,S) f32 [4M].
// ws layout (bytes): qb 0..8M, kb 8M..16M, vb 16M..24M, vT 24M..32M,
//                    attn_b 32M..40M, WT 40M..46M, owb 46M..48M.  (needs 48MB)
// NOTE: qb holds q * 0.125 * log2(e)  (log2-domain softmax; avg_w GEMM divides it out)

typedef __bf16 bf16;
typedef float f32x4 __attribute__((ext_vector_type(4)));
typedef float float4v __attribute__((ext_vector_type(4)));
typedef bf16 bf16x8 __attribute__((ext_vector_type(8)));
typedef bf16 bf16x4 __attribute__((ext_vector_type(4)));

#define LOG2E 1.4426950408889634f

// ---------------- prep kernels ----------------

// dst[sec][j][i] = (bf16) src[sec*1024 + i][j]   (per-1024x1024-section transpose)
__global__ __launch_bounds__(256) void transpose_f32_to_bf16(
    const float* __restrict__ src, bf16* __restrict__ dst, int dim) {
  __shared__ bf16 tile[64][72];
  int sec = blockIdx.z;
  int i0 = blockIdx.y * 64, j0 = blockIdx.x * 64;
  const float* s = src + (long)sec * dim * dim;
  bf16* d = dst + (long)sec * dim * dim;
  int t = threadIdx.x;
#pragma unroll
  for (int p = 0; p < 4; p++) {
    int ri = (t >> 4) + p * 16, cj = (t & 15) * 4;
    float4v v = *(const float4v*)(s + (long)(i0 + ri) * dim + j0 + cj);
    bf16x4 bv = { (bf16)v.x, (bf16)v.y, (bf16)v.z, (bf16)v.w };
    *(bf16x4*)&tile[ri][cj] = bv;
  }
  __syncthreads();
#pragma unroll
  for (int p = 0; p < 4; p++) {
    int rj = (t >> 4) + p * 16, ci = (t & 15) * 4;
    bf16x4 bv = { tile[ci][rj], tile[ci + 1][rj], tile[ci + 2][rj], tile[ci + 3][rj] };
    *(bf16x4*)&d[(long)(j0 + rj) * dim + i0 + ci] = bv;
  }
}

__global__ __launch_bounds__(256) void conv_f32_bf16(
    const float* __restrict__ src, bf16* __restrict__ dst, int n) {
  int i = (blockIdx.x * 256 + threadIdx.x) * 4;
  if (i < n) {
    float4v v = *(const float4v*)(src + i);
    bf16x4 bv = { (bf16)v.x, (bf16)v.y, (bf16)v.z, (bf16)v.w };
    *(bf16x4*)&dst[i] = bv;
  }
}

// vT[(b*1024 + j)*1024 + s] = vb[(s*4 + b)*1024 + j]
__global__ __launch_bounds__(256) void transpose_v(
    const bf16* __restrict__ vb, bf16* __restrict__ vT) {
  __shared__ bf16 tile[64][72];
  int b = blockIdx.z;
  int s0 = blockIdx.x * 64, j0 = blockIdx.y * 64;
  int t = threadIdx.x;
#pragma unroll
  for (int p = 0; p < 2; p++) {
    int si = (t >> 3) + p * 32, jj = (t & 7) * 8;
    bf16x8 v = *(const bf16x8*)&vb[((long)(s0 + si) * 4 + b) * 1024 + j0 + jj];
    *(bf16x8*)&tile[si][jj] = v;
  }
  __syncthreads();
#pragma unroll
  for (int p = 0; p < 2; p++) {
    int jj = (t >> 3) + p * 32, si = (t & 7) * 8;
    bf16 tmp[8];
#pragma unroll
    for (int q = 0; q < 8; q++) tmp[q] = tile[si + q][jj];
    *(bf16x8*)&vT[((long)b * 1024 + j0 + jj) * 1024 + s0 + si] = *(bf16x8*)tmp;
  }
}

// ---------------- shared NT GEMM body (512 threads, 8 waves, 128x128 tile) ----
// C[m][n] = scale * ( sum_k A[m][k]*B[n][k] + bias[n] ),  BK=32.
// wave w owns a 32x64 sub-tile: mq=(w>>1)*32, nq=(w&1)*64, acc[2][4].
template <bool A_F32, bool C_BF16>
__device__ __forceinline__ void gemm_body(
    const void* __restrict__ Av, long lda,
    const bf16* __restrict__ B, long ldb,
    void* __restrict__ Cv, long ldc,
    const float* __restrict__ bias, float scale, int K, int m0, int n0) {
  __shared__ bf16 sA[128][40];  // +8 pad
  __shared__ bf16 sB[128][40];
  int t = threadIdx.x;
  int w = t >> 6, lane = t & 63, r = lane & 15, g = lane >> 4;
  int mq = (w >> 1) * 32, nq = (w & 1) * 64;

  f32x4 acc[2][4];
#pragma unroll
  for (int mi = 0; mi < 2; mi++)
#pragma unroll
    for (int ni = 0; ni < 4; ni++) acc[mi][ni] = (f32x4){0.f, 0.f, 0.f, 0.f};

  for (int k0 = 0; k0 < K; k0 += 32) {
    if (A_F32) {
      const float* Ap = (const float*)Av;
      int row = t >> 3, col = (t & 7) * 4;
#pragma unroll
      for (int p = 0; p < 2; p++) {
        float4v v = *(const float4v*)(Ap + (long)(m0 + row + p * 64) * lda + k0 + col);
        bf16x4 bv = { (bf16)v.x, (bf16)v.y, (bf16)v.z, (bf16)v.w };
        *(bf16x4*)&sA[row + p * 64][col] = bv;
      }
    } else {
      const bf16* Ap = (const bf16*)Av;
      int row = t >> 2, col = (t & 3) * 8;
      bf16x8 v = *(const bf16x8*)(Ap + (long)(m0 + row) * lda + k0 + col);
      *(bf16x8*)&sA[row][col] = v;
    }
    {
      int row = t >> 2, col = (t & 3) * 8;
      bf16x8 v = *(const bf16x8*)(B + (long)(n0 + row) * ldb + k0 + col);
      *(bf16x8*)&sB[row][col] = v;
    }
    __syncthreads();
    bf16x8 af[2], bfr[4];
#pragma unroll
    for (int mi = 0; mi < 2; mi++) af[mi] = *(bf16x8*)&sA[mq + mi * 16 + r][g * 8];
#pragma unroll
    for (int ni = 0; ni < 4; ni++) bfr[ni] = *(bf16x8*)&sB[nq + ni * 16 + r][g * 8];
#pragma unroll
    for (int mi = 0; mi < 2; mi++)
#pragma unroll
      for (int ni = 0; ni < 4; ni++)
        acc[mi][ni] = __builtin_amdgcn_mfma_f32_16x16x32_bf16(af[mi], bfr[ni], acc[mi][ni], 0, 0, 0);
    __syncthreads();
  }

#pragma unroll
  for (int mi = 0; mi < 2; mi++)
#pragma unroll
    for (int ni = 0; ni < 4; ni++) {
      int col = n0 + nq + ni * 16 + r;
      float bv = bias ? bias[col] : 0.f;
#pragma unroll
      for (int j = 0; j < 4; j++) {
        int row = m0 + mq + mi * 16 + g * 4 + j;
        float val = (acc[mi][ni][j] + bv) * scale;
        if (C_BF16)
          ((bf16*)Cv)[(long)row * ldc + col] = (bf16)val;
        else
          ((float*)Cv)[(long)row * ldc + col] = val;
      }
    }
}

template <bool A_F32, bool C_BF16>
__global__ __launch_bounds__(512) void gemm_nt(
    const void* __restrict__ Av, long lda, long sAz,
    const bf16* __restrict__ B, long ldb, long sBz,
    void* __restrict__ Cv, long ldc, long sCz,
    const float* __restrict__ bias, float scale, int K) {
  int z = blockIdx.z;
  const char* Ap = (const char*)Av + (long)z * sAz * (A_F32 ? 4 : 2);
  const bf16* Bp = B + (long)z * sBz;
  char* Cp = (char*)Cv + (long)z * sCz * (C_BF16 ? 2 : 4);
  gemm_body<A_F32, C_BF16>(Ap, lda, Bp, ldb, Cp, ldc, bias, scale, K,
                           blockIdx.y * 128, blockIdx.x * 128);
}

// fused q/k/v projection: z selects input & weight section
__global__ __launch_bounds__(512) void gemm_proj(
    const float* __restrict__ q, const float* __restrict__ k,
    const float* __restrict__ v, const bf16* __restrict__ WT,
    const float* __restrict__ bias, bf16* __restrict__ out) {
  int z = blockIdx.z;
  const float* A = (z == 0) ? q : ((z == 1) ? k : v);
  const bf16* B = WT + (long)z * 1048576;
  const float* bz = bias + z * 1024;
  bf16* C = out + (long)z * 4194304;
  float scale = (z == 0) ? 0.125f * LOG2E : 1.0f;  // q carries log2(e) for exp2 softmax
  gemm_body<true, true>(A, 1024, B, 1024, C, 1024, bz, scale, 1024,
                        blockIdx.y * 128, blockIdx.x * 128);
}

// ---------------- fused dual-softmax flash attention (v4: pipelined) ---------
// grid (B*H, T/64); 4 waves, wave w owns 16 t-rows. No barriers (wave-private
// P exchange). K register double-buffer (prefetch next tile), V issued early,
// log2-domain softmax (qb pre-scaled by log2e, single v_exp_f32 per element).
__global__ __launch_bounds__(256, 4) void attn_fused(
    const bf16* __restrict__ qb, const bf16* __restrict__ kb,
    const bf16* __restrict__ vT, bf16* __restrict__ attn_b) {
  __shared__ bf16 sPp[4][16][72];
  __shared__ bf16 sPn[4][16][72];
  int bh = blockIdx.x;
  int b = bh >> 4, h = bh & 15;
  int t0 = blockIdx.y * 64;
  int t = threadIdx.x, w = t >> 6, lane = t & 63, r = lane & 15, g = lane >> 4;
  int tw = t0 + w * 16;

  // Q fragment (B-operand of swapped QK^T): lane (r,g) holds Q[t=tw+r][kk*32+g*8 ..+7]
  bf16x8 aq[2];
#pragma unroll
  for (int kk = 0; kk < 2; kk++)
    aq[kk] = *(const bf16x8*)&qb[((long)(tw + r) * 4 + b) * 1024 + h * 64 + kk * 32 + g * 8];

  // stats per t = r (replicated across g); O accumulators per t = g*4+j
  float m_p = -1e30f, l_p = 0.f, m_n = -1e30f, l_n = 0.f;
  f32x4 o_p[2], o_n[2];
#pragma unroll
  for (int ni = 0; ni < 2; ni++) {
    o_p[ni] = (f32x4){0.f, 0.f, 0.f, 0.f};
    o_n[ni] = (f32x4){0.f, 0.f, 0.f, 0.f};
  }

  const long kbase = (long)b * 1024 + h * 64 + g * 8;      // + s*4096
  const long vbase = ((long)b * 1024 + h * 32 + r) * 1024 + g * 8;
  const long vnoff = 512L * 1024;                          // decorr half of vT

  // prologue: K tile 0 into kA
  bf16x8 kA[8], kB[8];
#pragma unroll
  for (int sf = 0; sf < 4; sf++) {
    const bf16* kp = kb + (long)(sf * 16 + r) * 4096 + kbase;
    kA[2 * sf] = *(const bf16x8*)kp;
    kA[2 * sf + 1] = *(const bf16x8*)(kp + 32);
  }

  auto body = [&](int st, bf16x8* kc, bf16x8* kn) {
    int sb = st * 64;
    int sn = ((st + 1) & 15) * 64;  // wrap on last iter: harmless reload of tile 0
    // ---- prefetch next K tile (consumed next body call -> latency hidden) ----
#pragma unroll
    for (int sf = 0; sf < 4; sf++) {
      const bf16* kp = kb + (long)(sn + sf * 16 + r) * 4096 + kbase;
      kn[2 * sf] = *(const bf16x8*)kp;
      kn[2 * sf + 1] = *(const bf16x8*)(kp + 32);
    }
    // ---- QK^T swapped: sc[sf][j] = score2[t=r][s = sb + sf*16 + g*4 + j] ----
    f32x4 sc[4];
#pragma unroll
    for (int sf = 0; sf < 4; sf++) {
      f32x4 z = (f32x4){0.f, 0.f, 0.f, 0.f};
      z = __builtin_amdgcn_mfma_f32_16x16x32_bf16(kc[2 * sf], aq[0], z, 0, 0, 0);
      z = __builtin_amdgcn_mfma_f32_16x16x32_bf16(kc[2 * sf + 1], aq[1], z, 0, 0, 0);
      sc[sf] = z;
    }
    // ---- issue corr-V loads early (hidden under softmax VALU) ----
    bf16x8 vP[2][2];
#pragma unroll
    for (int c = 0; c < 2; c++)
#pragma unroll
      for (int ni = 0; ni < 2; ni++)
        vP[c][ni] = *(const bf16x8*)&vT[vbase + (long)ni * 16384 + sb + c * 32];
    // ---- dual online softmax (log2 domain) for row t=r ----
    float mx = sc[0][0], mn = sc[0][0];
#pragma unroll
    for (int sf = 0; sf < 4; sf++)
#pragma unroll
      for (int j = 0; j < 4; j++) {
        mx = fmaxf(mx, sc[sf][j]);
        mn = fminf(mn, sc[sf][j]);
      }
    mx = fmaxf(mx, __shfl_xor(mx, 16)); mx = fmaxf(mx, __shfl_xor(mx, 32));
    mn = fminf(mn, __shfl_xor(mn, 16)); mn = fminf(mn, __shfl_xor(mn, 32));
    float np = fmaxf(m_p, mx), nn = fmaxf(m_n, -mn);
    float alp = __builtin_amdgcn_exp2f(m_p - np);
    float aln = __builtin_amdgcn_exp2f(m_n - nn);
    m_p = np; m_n = nn;
    float sp = 0.f, sn2 = 0.f;
#pragma unroll
    for (int sf = 0; sf < 4; sf++) {
      float e0 = __builtin_amdgcn_exp2f(sc[sf][0] - np);
      float e1 = __builtin_amdgcn_exp2f(sc[sf][1] - np);
      float e2 = __builtin_amdgcn_exp2f(sc[sf][2] - np);
      float e3 = __builtin_amdgcn_exp2f(sc[sf][3] - np);
      sp += (e0 + e1) + (e2 + e3);
      bf16x4 pv = { (bf16)e0, (bf16)e1, (bf16)e2, (bf16)e3 };
      *(bf16x4*)&sPp[w][r][sf * 16 + g * 4] = pv;
      float f0 = __builtin_amdgcn_exp2f(-sc[sf][0] - nn);
      float f1 = __builtin_amdgcn_exp2f(-sc[sf][1] - nn);
      float f2 = __builtin_amdgcn_exp2f(-sc[sf][2] - nn);
      float f3 = __builtin_amdgcn_exp2f(-sc[sf][3] - nn);
      sn2 += (f0 + f1) + (f2 + f3);
      bf16x4 fv = { (bf16)f0, (bf16)f1, (bf16)f2, (bf16)f3 };
      *(bf16x4*)&sPn[w][r][sf * 16 + g * 4] = fv;
    }
    // ---- issue decorr-V loads (hidden under reduce+rescale+corr PV) ----
    bf16x8 vN[2][2];
#pragma unroll
    for (int c = 0; c < 2; c++)
#pragma unroll
      for (int ni = 0; ni < 2; ni++)
        vN[c][ni] = *(const bf16x8*)&vT[vbase + vnoff + (long)ni * 16384 + sb + c * 32];
    sp += __shfl_xor(sp, 16); sp += __shfl_xor(sp, 32);
    sn2 += __shfl_xor(sn2, 16); sn2 += __shfl_xor(sn2, 32);
    l_p = l_p * alp + sp;
    l_n = l_n * aln + sn2;
    // ---- rescale O (alpha for t = g*4+j is held by lane g*16 + g*4+j) ----
#pragma unroll
    for (int j = 0; j < 4; j++) {
      float aj = __shfl(alp, g * 20 + j);
      float bj = __shfl(aln, g * 20 + j);
      o_p[0][j] *= aj; o_p[1][j] *= aj;
      o_n[0][j] *= bj; o_n[1][j] *= bj;
    }
    // ---- PV: A-frag from wave-private LDS (b128), B-frag from preloaded regs ----
#pragma unroll
    for (int c = 0; c < 2; c++) {
      bf16x8 apP = *(bf16x8*)&sPp[w][r][c * 32 + g * 8];
      bf16x8 apN = *(bf16x8*)&sPn[w][r][c * 32 + g * 8];
#pragma unroll
      for (int ni = 0; ni < 2; ni++) {
        o_p[ni] = __builtin_amdgcn_mfma_f32_16x16x32_bf16(apP, vP[c][ni], o_p[ni], 0, 0, 0);
        o_n[ni] = __builtin_amdgcn_mfma_f32_16x16x32_bf16(apN, vN[c][ni], o_n[ni], 0, 0, 0);
      }
    }
  };

#pragma unroll 1
  for (int stp = 0; stp < 8; stp++) {
    body(2 * stp, kA, kB);
    body(2 * stp + 1, kB, kA);
  }

  // ---- epilogue: divide by l (per t = g*4+j) and store ----
#pragma unroll
  for (int j = 0; j < 4; j++) {
    float lpj = __shfl(l_p, g * 20 + j);
    float lnj = __shfl(l_n, g * 20 + j);
    float rp = 1.0f / lpj, rn = 1.0f / lnj;
    int trow = tw + g * 4 + j;
    long base = ((long)trow * 4 + b) * 1024 + h * 64;
#pragma unroll
    for (int ni = 0; ni < 2; ni++) {
      attn_b[base + ni * 16 + r] = (bf16)(o_p[ni][j] * rp);
      attn_b[base + 32 + ni * 16 + r] = (bf16)(o_n[ni][j] * rn);
    }
  }
}

// ---------------- launcher ----------------
extern "C" void kernel_launch(void* const* d_in, const int* in_sizes, int n_in,
                              void* d_out, int out_size, void* d_ws, size_t ws_size,
                              hipStream_t stream) {
  (void)in_sizes; (void)n_in; (void)out_size; (void)ws_size;
  const float* query = (const float*)d_in[0];
  const float* key   = (const float*)d_in[1];
  const float* value = (const float*)d_in[2];
  const float* W     = (const float*)d_in[3];
  const float* bias  = (const float*)d_in[4];
  const float* out_w = (const float*)d_in[5];
  const float* out_b = (const float*)d_in[6];

  char* ws = (char*)d_ws;
  const long MB = 1 << 20;
  bf16* qb  = (bf16*)(ws + 0 * MB);
  bf16* kb  = (bf16*)(ws + 8 * MB);
  bf16* vb  = (bf16*)(ws + 16 * MB);
  bf16* vT  = (bf16*)(ws + 24 * MB);
  bf16* ab  = (bf16*)(ws + 32 * MB);
  bf16* WT  = (bf16*)(ws + 40 * MB);
  bf16* owb = (bf16*)(ws + 46 * MB);
  float* out_attn = (float*)d_out;
  float* out_avg  = (float*)d_out + (size_t)4 * 1024 * 1024;
  const long M1 = 1024L * 1024L;

  transpose_f32_to_bf16<<<dim3(16, 16, 3), 256, 0, stream>>>(W, WT, 1024);
  conv_f32_bf16<<<dim3(1024), 256, 0, stream>>>(out_w, owb, 1024 * 1024);

  // fused projections: q (scaled 0.125*log2e), k, v — one launch, 768 blocks x 8 waves
  gemm_proj<<<dim3(8, 32, 3), 512, 0, stream>>>(query, key, value, WT, bias, qb);

  transpose_v<<<dim3(16, 16, 4), 256, 0, stream>>>(vb, vT);

  // avg_w[b,t,s] = (1/16) * sum_e q_scaled[t,b,e] * k[s,b,e];  qb carries log2e -> divide out
  gemm_nt<false, false><<<dim3(8, 8, 4), 512, 0, stream>>>(
      qb, 4096, 1024, kb, 4096, 1024, out_avg, 1024, M1, nullptr, 1.f / (16.f * LOG2E), 1024);

  attn_fused<<<dim3(64, 16), 256, 0, stream>>>(qb, kb, vT, ab);

  // out projection: C = attn @ out_w^T + out_b
  gemm_nt<false, false><<<dim3(8, 32, 1), 512, 0, stream>>>(
      ab, 1024, 0, owb, 1024, 0, out_attn, 1024, 0, out_b, 1.0f, 1024);
}